// Round 1
// baseline (226.518 us; speedup 1.0000x reference)
//
#include <hip/hip_runtime.h>
#include <hip/hip_bf16.h>

// DCNv2 forward, fp32 baseline.
// N=4, IN_C=128, OUT_C=128, H=W=64, K=3, STRIDE=1, PAD=1, taps=9.
// Pipeline: offconv -> posprep -> wtrans -> dcn_main (GEMM M=16384,O=128,K=1152) -> combine.

#define NB    4
#define CIN   128
#define HH    64
#define WW    64
#define TAPS  9
#define OCH   27          // offset conv channels (3*9)
#define OUTC  128
#define NPOS  (NB*HH*WW)  // 16384

// ---------------- kernel 1: offset conv, 4-way channel-split partials ----------------
// grid: 256 blocks = 64 rowgroups x 4 cgroups; block: 256 = 4 rows x 64 w
__global__ __launch_bounds__(256) void offconv(const float* __restrict__ x,
                                               const float* __restrict__ ofw,
                                               float* __restrict__ part) {
    int bid = blockIdx.x;
    int rg = bid >> 2, cg = bid & 3;
    int tid = threadIdx.x;
    int lr = tid >> 6, ow = tid & 63;
    int row = rg * 4 + lr;            // n*64 + oh
    int n = row >> 6, oh = row & 63;
    int c0 = cg * 32;

    __shared__ float wl[32 * 9 * 27]; // [c_local][t][oc], 31.1 KB
    for (int i = tid; i < 32 * 9 * 27; i += 256) {
        int cl = i / 243, rem = i % 243;
        int t = rem / 27, oc = rem % 27;
        wl[i] = ofw[(oc * CIN + c0 + cl) * 9 + t];
    }
    __syncthreads();

    float acc[27];
#pragma unroll
    for (int oc = 0; oc < 27; ++oc) acc[oc] = 0.f;

    const float* xb0 = x + (((n * CIN + c0) << 12) + (oh << 6) + ow);
    for (int cl = 0; cl < 32; ++cl) {
        const float* xb = xb0 + (cl << 12);
        float xv[9];
#pragma unroll
        for (int kh = 0; kh < 3; ++kh) {
            int ih = oh + kh - 1;
            bool okr = (unsigned)ih < 64u;
#pragma unroll
            for (int kw = 0; kw < 3; ++kw) {
                int iw = ow + kw - 1;
                bool ok = okr && ((unsigned)iw < 64u);
                xv[kh * 3 + kw] = ok ? xb[(kh - 1) * 64 + (kw - 1)] : 0.f;
            }
        }
        const float* wrow = &wl[cl * 243];
#pragma unroll
        for (int t = 0; t < 9; ++t) {
            float xvt = xv[t];
#pragma unroll
            for (int oc = 0; oc < 27; ++oc)
                acc[oc] = fmaf(xvt, wrow[t * 27 + oc], acc[oc]);
        }
    }

    int sp = (oh << 6) + ow;
#pragma unroll
    for (int oc = 0; oc < 27; ++oc)
        part[(((cg * 4 + n) * 27 + oc) << 12) + sp] = acc[oc];
}

// ---------------- kernel 2: reduce partials -> per-(pos,tap) meta ----------------
// grid: 64 blocks x 256 threads, one thread per position
__global__ __launch_bounds__(256) void posprep(const float* __restrict__ part,
                                               const float* __restrict__ ob,
                                               float4* __restrict__ wq_t,
                                               ushort4* __restrict__ yx_t) {
    int gid = blockIdx.x * 256 + threadIdx.x;   // < 16384
    int n = gid >> 12, sp = gid & 4095;
    int oh = sp >> 6, ow = sp & 63;

    float om[27];
#pragma unroll
    for (int oc = 0; oc < 27; ++oc) {
        float s = ob[oc];
#pragma unroll
        for (int cg = 0; cg < 4; ++cg)
            s += part[(((cg * 4 + n) * 27 + oc) << 12) + sp];
        om[oc] = s;
    }

#pragma unroll
    for (int k = 0; k < 9; ++k) {
        float oy = om[2 * k], ox = om[2 * k + 1];
        float m = 1.f / (1.f + expf(-om[18 + k]));
        // base + inner: oh+1 + (k/3 - 1) = oh + k/3 ; clip to [0, 65]
        float py = fminf(fmaxf((float)(oh + k / 3) + oy, 0.f), 65.f);
        float px = fminf(fmaxf((float)(ow + k % 3) + ox, 0.f), 65.f);
        float y1f = floorf(py), x1f = floorf(px);
        float lh = py - y1f, lw = px - x1f;
        float hh = 1.f - lh, hw = 1.f - lw;
        int y1 = (int)y1f, x1 = (int)x1f;
        // padded coord -> real row/col: r = ypad - 1 ; y2 = y1+1 -> row y1
        int r1 = y1 - 1, r2 = y1;
        int c1 = x1 - 1, c2 = x1;
        bool vr1 = (unsigned)r1 < 64u, vr2 = (unsigned)r2 < 64u;
        bool vc1 = (unsigned)c1 < 64u, vc2 = (unsigned)c2 < 64u;
        float w1 = (vr1 && vc1) ? hh * hw * m : 0.f;
        float w2 = (vr1 && vc2) ? hh * lw * m : 0.f;
        float w3 = (vr2 && vc1) ? lh * hw * m : 0.f;
        float w4 = (vr2 && vc2) ? lh * lw * m : 0.f;
        int R1 = min(max(r1, 0), 63), R2 = min(max(r2, 0), 63);
        int C1 = min(max(c1, 0), 63), C2 = min(max(c2, 0), 63);
        wq_t[(k << 14) + gid] = make_float4(w1, w2, w3, w4);
        yx_t[(k << 14) + gid] = make_ushort4((unsigned short)R1, (unsigned short)R2,
                                             (unsigned short)C1, (unsigned short)C2);
    }
}

// ---------------- kernel 3: dcn_w [o][c][t] -> wt [t][c][o] ----------------
__global__ __launch_bounds__(256) void wtrans(const float* __restrict__ dcn_w,
                                              float* __restrict__ wt) {
    int i = blockIdx.x * 256 + threadIdx.x;  // < 147456 = 576*256
    int t = i >> 14, rem = i & 16383;
    int c = rem >> 7, o = rem & 127;
    wt[i] = dcn_w[((o << 7) + c) * 9 + t];
}

// ---------------- kernel 4: fused gather + GEMM ----------------
// grid: 512 blocks = 128 pos-tiles x 4 K-quarters; block 256 threads
// block tile: 128 pos x 128 out; thread tile 8x8; K-quarter = 9 taps x 32 ch
__global__ __launch_bounds__(256) void dcn_main(const float* __restrict__ x,
                                                const float4* __restrict__ wq_t,
                                                const ushort4* __restrict__ yx_t,
                                                const float* __restrict__ wt,
                                                float* __restrict__ pout) {
    __shared__ float As[16][128];
    __shared__ float Bs[16][128];

    int bid = blockIdx.x;
    int tile = bid >> 2, kq = bid & 3;
    int p0 = tile << 7;
    int tid = threadIdx.x;
    int lp = tid & 127, hi = tid >> 7;     // staging: fixed pos, 8 channels
    int pos = p0 + lp;
    const float* xn = x + ((pos >> 12) << 19);   // n*CIN*H*W
    int tp8 = (tid >> 4) << 3, to8 = (tid & 15) << 3;

    float acc[8][8];
#pragma unroll
    for (int i = 0; i < 8; ++i)
#pragma unroll
        for (int j = 0; j < 8; ++j) acc[i][j] = 0.f;

    for (int t = 0; t < 9; ++t) {
        float4 wv = wq_t[(t << 14) + pos];
        ushort4 yx = yx_t[(t << 14) + pos];
        int o1 = ((int)yx.x << 6) + (int)yx.z;
        int o2 = ((int)yx.x << 6) + (int)yx.w;
        int o3 = ((int)yx.y << 6) + (int)yx.z;
        int o4 = ((int)yx.y << 6) + (int)yx.w;
#pragma unroll
        for (int cc = 0; cc < 2; ++cc) {
            int c0 = (kq << 5) + (cc << 4);
            // stage B: contiguous 16c x 128o slab of wt
            const float4* bsrc = (const float4*)(wt + (t << 14) + (c0 << 7));
            ((float4*)&Bs[0][0])[tid] = bsrc[tid];
            ((float4*)&Bs[0][0])[tid + 256] = bsrc[tid + 256];
            // stage A: bilinear gather (mask & OOB already folded into wv)
#pragma unroll
            for (int j = 0; j < 8; ++j) {
                int cl = hi + (j << 1);
                const float* xb = xn + ((c0 + cl) << 12);
                float v = wv.x * xb[o1] + wv.y * xb[o2] + wv.z * xb[o3] + wv.w * xb[o4];
                As[cl][lp] = v;
            }
            __syncthreads();
#pragma unroll
            for (int kk = 0; kk < 16; ++kk) {
                float a[8], b[8];
                *(float4*)&a[0] = *(const float4*)&As[kk][tp8];
                *(float4*)&a[4] = *(const float4*)&As[kk][tp8 + 4];
                *(float4*)&b[0] = *(const float4*)&Bs[kk][to8];
                *(float4*)&b[4] = *(const float4*)&Bs[kk][to8 + 4];
#pragma unroll
                for (int i = 0; i < 8; ++i)
#pragma unroll
                    for (int j = 0; j < 8; ++j)
                        acc[i][j] = fmaf(a[i], b[j], acc[i][j]);
            }
            __syncthreads();
        }
    }

    // epilogue: pout[kq][pos][o], coalesced float4 stores
    float* op = pout + (kq << 21);
#pragma unroll
    for (int i = 0; i < 8; ++i) {
        float* dst = op + ((p0 + tp8 + i) << 7) + to8;
        float4 v0 = make_float4(acc[i][0], acc[i][1], acc[i][2], acc[i][3]);
        float4 v1 = make_float4(acc[i][4], acc[i][5], acc[i][6], acc[i][7]);
        *(float4*)dst = v0;
        *(float4*)(dst + 4) = v1;
    }
}

// ---------------- kernel 5: sum K-partials + transpose to NCHW ----------------
// grid: 256 blocks (one per (n,oh) row) x 256 threads
__global__ __launch_bounds__(256) void combine(const float* __restrict__ pout,
                                               float* __restrict__ out) {
    __shared__ float tileS[64 * 129];
    int row = blockIdx.x;              // n*64 + oh
    int n = row >> 6, oh = row & 63;
    int pbase = row << 6;
#pragma unroll
    for (int it = 0; it < 32; ++it) {
        int flat = it * 256 + threadIdx.x;   // [0, 8192)
        int pl = flat >> 7, o = flat & 127;
        int pidx = ((pbase + pl) << 7) + o;
        float s = pout[pidx] + pout[pidx + (1 << 21)] +
                  pout[pidx + (2 << 21)] + pout[pidx + (3 << 21)];
        tileS[pl * 129 + o] = s;
    }
    __syncthreads();
#pragma unroll
    for (int it = 0; it < 32; ++it) {
        int flat = it * 256 + threadIdx.x;
        int ow = flat & 63, o = flat >> 6;
        out[(((n << 7) + o) << 12) + (oh << 6) + ow] = tileS[ow * 129 + o];
    }
}

extern "C" void kernel_launch(void* const* d_in, const int* in_sizes, int n_in,
                              void* d_out, int out_size, void* d_ws, size_t ws_size,
                              hipStream_t stream) {
    const float* x     = (const float*)d_in[0];   // [4,128,64,64]
    const float* ofw   = (const float*)d_in[1];   // [27,128,3,3]
    const float* ob    = (const float*)d_in[2];   // [27]
    const float* dcn_w = (const float*)d_in[3];   // [128,128,3,3]
    float* out = (float*)d_out;                   // [4,128,64,64]

    char* ws = (char*)d_ws;
    // ws layout (bytes, all 16B aligned):
    float*   part = (float*)(ws);                          // 4*4*27*4096 f = 7,077,888 B
    float4*  wq_t = (float4*)(ws + 7077888);               // 9*16384 float4 = 2,359,296 B
    ushort4* yx_t = (ushort4*)(ws + 9437184);              // 9*16384 * 8B  = 1,179,648 B
    float*   wt   = (float*)(ws + 10616832);               // 147456 f      =   589,824 B
    float*   pout = (float*)(ws + 11206656);               // 4*16384*128 f = 33,554,432 B
    // total ws use: 44,761,088 B

    offconv<<<dim3(256), dim3(256), 0, stream>>>(x, ofw, part);
    posprep<<<dim3(64), dim3(256), 0, stream>>>(part, ob, wq_t, yx_t);
    wtrans<<<dim3(576), dim3(256), 0, stream>>>(dcn_w, wt);
    dcn_main<<<dim3(512), dim3(256), 0, stream>>>(x, wq_t, yx_t, wt, pout);
    combine<<<dim3(256), dim3(256), 0, stream>>>(pout, out);
}

// Round 3
// 197.629 us; speedup vs baseline: 1.1462x; 1.1462x over previous
//
#include <hip/hip_runtime.h>

// DCNv2 forward, fp32 v2 (resubmit — R2 bench was an acquisition timeout).
// Pipeline: wtrans (weight transposes) -> offconv (scalar-weight conv) ->
//           posprep (per-(tap,pos) meta) -> dcn_main (LDS GEMM, swizzled B, prefetch) -> combine.
// N=4, IN_C=128, OUT_C=128, H=W=64, K=3, taps=9. GEMM: M=16384, N=128, K=1152.

#define CIN   128

// f4-index swizzle within a 32-f4 LDS row: XOR bit0 with bit3 -> B-reads 2-way (free)
#define SWZ4(c) ((c) ^ (((c) >> 3) & 1))

// ---------------- kernel 0: weight transposes ----------------
// wt[t][c][o] <- dcn_w[o][c][t] (147456) ; ofwT[c][t*27+oc] <- ofw[oc][c][t] (31104)
__global__ __launch_bounds__(256) void wtrans(const float* __restrict__ ofw,
                                              const float* __restrict__ dcn_w,
                                              float* __restrict__ wt,
                                              float* __restrict__ ofwT) {
    int i = blockIdx.x * 256 + threadIdx.x;      // < 147456
    {
        int t = i >> 14, rem = i & 16383, c = rem >> 7, o = rem & 127;
        wt[i] = dcn_w[((o << 7) + c) * 9 + t];
    }
    if (i < 31104) {
        int c = i / 243, rem = i % 243, t = rem / 27, oc = rem % 27;
        ofwT[i] = ofw[((oc << 7) + c) * 9 + t];
    }
}

// ---------------- kernel 1: offset conv, 16 cgroups x 8ch, scalar weights ----------------
// grid 1024 = 64 rowgroups x 16 cgroups; block 256 = 4 rows x 64 w. No LDS.
__global__ __launch_bounds__(256) void offconv(const float* __restrict__ x,
                                               const float* __restrict__ ofwT,
                                               float* __restrict__ part) {
    int b0 = blockIdx.x;
    int bid = ((b0 & 7) << 7) | (b0 >> 3);       // XCD swizzle (1024 % 8 == 0)
    int rg = bid >> 4, cg = bid & 15;
    int tid = threadIdx.x;
    int lr = tid >> 6, ow = tid & 63;
    int row = (rg << 2) + lr;                    // n*64 + oh
    int n = row >> 6, oh = row & 63;
    int c0 = cg << 3;

    float acc[27];
#pragma unroll
    for (int oc = 0; oc < 27; ++oc) acc[oc] = 0.f;

    const float* xb0 = x + ((n * CIN + c0) << 12) + (oh << 6) + ow;
#pragma unroll 1
    for (int cl = 0; cl < 8; ++cl) {
        const float* xb = xb0 + (cl << 12);
        float xv[9];
#pragma unroll
        for (int kh = 0; kh < 3; ++kh) {
            int ih = oh + kh - 1;
            bool okr = ((unsigned)ih < 64u);
#pragma unroll
            for (int kw = 0; kw < 3; ++kw) {
                int iw = ow + kw - 1;
                xv[kh * 3 + kw] = (okr && (unsigned)iw < 64u) ? xb[(kh - 1) * 64 + (kw - 1)] : 0.f;
            }
        }
        // wave-uniform address -> compiler emits scalar (s_load) weight reads
        const float* wrow = ofwT + (c0 + cl) * 243;
#pragma unroll
        for (int t = 0; t < 9; ++t) {
            float xvt = xv[t];
#pragma unroll
            for (int oc = 0; oc < 27; ++oc)
                acc[oc] = fmaf(xvt, wrow[t * 27 + oc], acc[oc]);
        }
    }
    int sp = (oh << 6) + ow;
#pragma unroll
    for (int oc = 0; oc < 27; ++oc)
        part[((((cg << 2) + n) * 27 + oc) << 12) + sp] = acc[oc];
}

// ---------------- kernel 2: per-(tap,pos) meta ----------------
// grid 576 x 256; thread <-> (k, pos)
__global__ __launch_bounds__(256) void posprep(const float* __restrict__ part,
                                               const float* __restrict__ ob,
                                               float4* __restrict__ wq_t,
                                               ushort4* __restrict__ yx_t) {
    int gid = blockIdx.x * 256 + threadIdx.x;    // < 147456
    int k = gid >> 14, pos = gid & 16383;
    int n = pos >> 12, sp = pos & 4095;
    int oh = sp >> 6, ow = sp & 63;

    float oy = ob[2 * k], ox = ob[2 * k + 1], os = ob[18 + k];
#pragma unroll
    for (int cg = 0; cg < 16; ++cg) {
        const float* pb = part + (((((cg << 2) + n) * 27)) << 12) + sp;
        oy += pb[(2 * k) << 12];
        ox += pb[(2 * k + 1) << 12];
        os += pb[(18 + k) << 12];
    }
    float m = 1.f / (1.f + expf(-os));
    float py = fminf(fmaxf((float)(oh + k / 3) + oy, 0.f), 65.f);
    float px = fminf(fmaxf((float)(ow + k % 3) + ox, 0.f), 65.f);
    float y1f = floorf(py), x1f = floorf(px);
    float lh = py - y1f, lw = px - x1f;
    float hh = 1.f - lh, hw = 1.f - lw;
    int y1 = (int)y1f, x1 = (int)x1f;
    int r1 = y1 - 1, r2 = y1, c1 = x1 - 1, c2 = x1;   // padded -> real coords
    bool vr1 = (unsigned)r1 < 64u, vr2 = (unsigned)r2 < 64u;
    bool vc1 = (unsigned)c1 < 64u, vc2 = (unsigned)c2 < 64u;
    float w1 = (vr1 && vc1) ? hh * hw * m : 0.f;
    float w2 = (vr1 && vc2) ? hh * lw * m : 0.f;
    float w3 = (vr2 && vc1) ? lh * hw * m : 0.f;
    float w4 = (vr2 && vc2) ? lh * lw * m : 0.f;
    int R1 = min(max(r1, 0), 63), R2 = min(max(r2, 0), 63);
    int C1 = min(max(c1, 0), 63), C2 = min(max(c2, 0), 63);
    wq_t[(k << 14) + pos] = make_float4(w1, w2, w3, w4);
    yx_t[(k << 14) + pos] = make_ushort4((unsigned short)R1, (unsigned short)R2,
                                         (unsigned short)C1, (unsigned short)C2);
}

// ---------------- kernel 3: fused gather + GEMM ----------------
// grid 512 = 128 pos-tiles(128) x 4 kq(32ch). Block 256, 8x8 thread-tile.
// 18 phases (9 taps x 2 ch-halves of 16): single-barrier double-buffer,
// register prefetch of gathers/B-slab/meta one phase ahead, swizzled Bs.
__global__ __launch_bounds__(256, 2) void dcn_main(const float* __restrict__ x,
                                                   const float4* __restrict__ wq_t,
                                                   const ushort4* __restrict__ yx_t,
                                                   const float4* __restrict__ wt4,
                                                   float* __restrict__ pout) {
    __shared__ float As[2][16][128];
    __shared__ float Bs[2][16][128];

    int b0 = blockIdx.x;
    int bid = ((b0 & 7) << 6) | (b0 >> 3);       // XCD swizzle (512 % 8 == 0)
    int tile = bid >> 2, kq = bid & 3;
    int p0 = tile << 7;
    int kqb = kq << 5;                           // channel base
    int tid = threadIdx.x;
    int lp = tid & 127, hi = tid >> 7;           // staging: pos lp, channels (j<<1)|hi
    int pos = p0 + lp;
    int n = pos >> 12;
    const float* xn = x + ((long)n << 19);
    int tp8 = (tid >> 4) << 3, to8 = (tid & 15) << 3;
    int ar0 = tp8 >> 2;
    int br0 = SWZ4(to8 >> 2), br1 = SWZ4((to8 >> 2) + 1);

    float acc[8][8];
#pragma unroll
    for (int i = 0; i < 8; ++i)
#pragma unroll
        for (int j = 0; j < 8; ++j) acc[i][j] = 0.f;

    // prefetch state
    float4 wv;
    int o1, o2, o3, o4;
    float4 bp0, bp1;
    float g[8][4];

    // prologue: tap 0, half 0
    {
        wv = wq_t[pos];
        ushort4 yx = yx_t[pos];
        o1 = ((int)yx.x << 6) + yx.z; o2 = ((int)yx.x << 6) + yx.w;
        o3 = ((int)yx.y << 6) + yx.z; o4 = ((int)yx.y << 6) + yx.w;
        const float4* bsrc = wt4 + (kqb << 5);
        bp0 = bsrc[tid]; bp1 = bsrc[tid + 256];
#pragma unroll
        for (int j = 0; j < 8; ++j) {
            const float* xc = xn + ((kqb + ((j << 1) | hi)) << 12);
            g[j][0] = xc[o1]; g[j][1] = xc[o2]; g[j][2] = xc[o3]; g[j][3] = xc[o4];
        }
    }

    int cur = 0;
#pragma unroll 1
    for (int p = 0; p < 18; ++p) {
        // stage buf[cur] from prefetched regs
        {
            int r = tid >> 5, c = tid & 31;
            ((float4*)Bs[cur][r])[SWZ4(c)]     = bp0;
            ((float4*)Bs[cur][r + 8])[SWZ4(c)] = bp1;
#pragma unroll
            for (int j = 0; j < 8; ++j) {
                float v = wv.x * g[j][0] + wv.y * g[j][1] + wv.z * g[j][2] + wv.w * g[j][3];
                As[cur][(j << 1) | hi][lp] = v;
            }
        }
        __syncthreads();

        // prefetch phase p+1 (issued before FMA so latency hides under it)
        if (p < 17) {
            int pn = p + 1, tn = pn >> 1, c0n = kqb + ((pn & 1) << 4);
            if ((pn & 1) == 0) {
                wv = wq_t[(tn << 14) + pos];
                ushort4 yx = yx_t[(tn << 14) + pos];
                o1 = ((int)yx.x << 6) + yx.z; o2 = ((int)yx.x << 6) + yx.w;
                o3 = ((int)yx.y << 6) + yx.z; o4 = ((int)yx.y << 6) + yx.w;
            }
            const float4* bsrc = wt4 + (tn << 12) + (c0n << 5);
            bp0 = bsrc[tid]; bp1 = bsrc[tid + 256];
#pragma unroll
            for (int j = 0; j < 8; ++j) {
                const float* xc = xn + ((c0n + ((j << 1) | hi)) << 12);
                g[j][0] = xc[o1]; g[j][1] = xc[o2]; g[j][2] = xc[o3]; g[j][3] = xc[o4];
            }
        }

        // FMA on buf[cur]
        {
            const float4* A4 = (const float4*)As[cur][0];
            const float4* B4 = (const float4*)Bs[cur][0];
#pragma unroll
            for (int kk = 0; kk < 16; ++kk) {
                float4 a0 = A4[(kk << 5) + ar0], a1 = A4[(kk << 5) + ar0 + 1];
                float4 b0 = B4[(kk << 5) + br0], b1 = B4[(kk << 5) + br1];
                float a[8] = {a0.x, a0.y, a0.z, a0.w, a1.x, a1.y, a1.z, a1.w};
                float b[8] = {b0.x, b0.y, b0.z, b0.w, b1.x, b1.y, b1.z, b1.w};
#pragma unroll
                for (int i = 0; i < 8; ++i)
#pragma unroll
                    for (int j = 0; j < 8; ++j)
                        acc[i][j] = fmaf(a[i], b[j], acc[i][j]);
            }
        }
        cur ^= 1;
    }

    // epilogue: pout[kq][pos][o], coalesced f4 stores
    float* op = pout + ((long)kq << 21) + ((long)(p0 + tp8) << 7) + to8;
#pragma unroll
    for (int i = 0; i < 8; ++i) {
        *(float4*)(op + (i << 7))     = make_float4(acc[i][0], acc[i][1], acc[i][2], acc[i][3]);
        *(float4*)(op + (i << 7) + 4) = make_float4(acc[i][4], acc[i][5], acc[i][6], acc[i][7]);
    }
}

// ---------------- kernel 4: sum 4 K-partials + transpose to NCHW ----------------
// grid 256 (one per (n,oh) row) x 256
__global__ __launch_bounds__(256) void combine(const float* __restrict__ pout,
                                               float* __restrict__ out) {
    __shared__ float tileS[64 * 129];
    int row = blockIdx.x;
    int n = row >> 6, oh = row & 63;
    const float4* p4 = (const float4*)pout;
    long fb = (long)row << 11;                   // row*64*128/4
#pragma unroll
    for (int it = 0; it < 8; ++it) {
        int idx = it * 256 + threadIdx.x;        // 0..2047
        int pl = idx >> 5, c4 = idx & 31;
        long fi = fb + (pl << 5) + c4;
        float4 s0 = p4[fi];
        float4 s1 = p4[fi + (1L << 19)];
        float4 s2 = p4[fi + (2L << 19)];
        float4 s3 = p4[fi + (3L << 19)];
        int o = c4 << 2;
        float* tp = &tileS[pl * 129 + o];
        tp[0] = s0.x + s1.x + s2.x + s3.x;
        tp[1] = s0.y + s1.y + s2.y + s3.y;
        tp[2] = s0.z + s1.z + s2.z + s3.z;
        tp[3] = s0.w + s1.w + s2.w + s3.w;
    }
    __syncthreads();
#pragma unroll
    for (int it = 0; it < 32; ++it) {
        int flat = it * 256 + threadIdx.x;       // 0..8191
        int ow = flat & 63, o = flat >> 6;
        out[(((n << 7) + o) << 12) + (oh << 6) + ow] = tileS[ow * 129 + o];
    }
}

extern "C" void kernel_launch(void* const* d_in, const int* in_sizes, int n_in,
                              void* d_out, int out_size, void* d_ws, size_t ws_size,
                              hipStream_t stream) {
    const float* x     = (const float*)d_in[0];   // [4,128,64,64]
    const float* ofw   = (const float*)d_in[1];   // [27,128,3,3]
    const float* ob    = (const float*)d_in[2];   // [27]
    const float* dcn_w = (const float*)d_in[3];   // [128,128,3,3]
    float* out = (float*)d_out;                   // [4,128,64,64]

    char* ws = (char*)d_ws;
    // ws layout (pout and part overlap: part dead before dcn_main writes pout)
    float*   pout = (float*)ws;                   // 4*16384*128*4  = 33,554,432 B
    float*   part = (float*)ws;                   // 16*4*27*4096*4 = 28,311,552 B (overlap)
    float4*  wq_t = (float4*)(ws + 33554432);     // 9*16384*16 = 2,359,296 B
    ushort4* yx_t = (ushort4*)(ws + 35913728);    // 9*16384*8  = 1,179,648 B
    float*   wt   = (float*)(ws + 37093376);      // 147456*4   =   589,824 B
    float*   ofwT = (float*)(ws + 37683200);      // 31104*4    =   124,416 B
    // total: 37,807,616 B (< 44.7 MB proven budget)

    wtrans<<<dim3(576), dim3(256), 0, stream>>>(ofw, dcn_w, wt, ofwT);
    offconv<<<dim3(1024), dim3(256), 0, stream>>>(x, ofwT, part);
    posprep<<<dim3(576), dim3(256), 0, stream>>>(part, ob, wq_t, yx_t);
    dcn_main<<<dim3(512), dim3(256), 0, stream>>>(x, wq_t, yx_t, (const float4*)wt, pout);
    combine<<<dim3(256), dim3(256), 0, stream>>>(pout, out);
}

// Round 5
// 168.502 us; speedup vs baseline: 1.3443x; 1.1729x over previous
//
#include <hip/hip_runtime.h>

// DCNv2 forward v4.1 — MFMA bf16-split GEMM (fix: combine() call-site cast).
// K1 offconv_prep (conv 16-way chan-split + dcn_w bf16 hi/lo pre-swizzled prep)
// K2 posprep (per-(tap,pos) bilinear meta, mask/OOB folded)
// K3 dcn_main (MFMA 16x16x32 bf16, split hi/lo: AhBh+AlBh+AhBl; 512 blocks)
// K4 combine (sum 4 K-partials, coalesced, o-major -> NCHW is index-free)

#define CIN 128

typedef __attribute__((ext_vector_type(4))) float f32x4;
typedef __attribute__((ext_vector_type(8))) short bf16x8;

__device__ __forceinline__ unsigned short f2bf(float f) {
    unsigned u = __float_as_uint(f);
    u += 0x7FFF + ((u >> 16) & 1);          // RNE
    return (unsigned short)(u >> 16);
}
__device__ __forceinline__ float bf2f(unsigned short h) {
    return __uint_as_float(((unsigned)h) << 16);
}

// ---------------- K1: offset conv (blocks 0..1023) + weight prep (blocks 1024..1599) ----------------
// conv: 64 rowgroups x 16 cgroups(8ch); block 256 = 4 rows x 64 w; scalar weights direct from ofw.
// prep: wbh/wbl[S=36][o=128][Gslot=4][e=8] bf16, ch pre-swizzled: c=(S&3)*32+((G^(o&3))<<3)+e, t=S>>2.
__global__ __launch_bounds__(256) void offconv_prep(const float* __restrict__ x,
                                                    const float* __restrict__ ofw,
                                                    const float* __restrict__ dcn_w,
                                                    float* __restrict__ part,
                                                    unsigned short* __restrict__ wbh,
                                                    unsigned short* __restrict__ wbl) {
    int bid = blockIdx.x;
    int tid = threadIdx.x;
    if (bid >= 1024) {
        int i = (bid - 1024) * 256 + tid;            // < 147456
        int S = i >> 12, rem = i & 4095;
        int o = rem >> 5, G = (rem >> 3) & 3, e = i & 7;
        int t = S >> 2;
        int c = ((S & 3) << 5) + ((G ^ (o & 3)) << 3) + e;
        float w = dcn_w[((o << 7) + c) * 9 + t];
        unsigned short h = f2bf(w);
        wbh[i] = h;
        wbl[i] = f2bf(w - bf2f(h));
        return;
    }
    int rg = bid >> 4, cg = bid & 15;
    int lr = tid >> 6, ow = tid & 63;
    int row = (rg << 2) + lr;                        // n*64 + oh
    int n = row >> 6, oh = row & 63;
    int c0 = cg << 3;

    float acc[27];
#pragma unroll
    for (int oc = 0; oc < 27; ++oc) acc[oc] = 0.f;

    const float* xb0 = x + ((n * CIN + c0) << 12) + (oh << 6) + ow;
#pragma unroll 1
    for (int cl = 0; cl < 8; ++cl) {
        const float* xb = xb0 + (cl << 12);
        float xv[9];
#pragma unroll
        for (int kh = 0; kh < 3; ++kh) {
            int ih = oh + kh - 1;
            bool okr = ((unsigned)ih < 64u);
#pragma unroll
            for (int kw = 0; kw < 3; ++kw) {
                int iw = ow + kw - 1;
                xv[kh * 3 + kw] = (okr && (unsigned)iw < 64u) ? xb[(kh - 1) * 64 + (kw - 1)] : 0.f;
            }
        }
        const float* wp = ofw + (c0 + cl) * 9;       // wave-uniform -> scalar loads
#pragma unroll
        for (int t = 0; t < 9; ++t) {
            float xvt = xv[t];
#pragma unroll
            for (int oc = 0; oc < 27; ++oc)
                acc[oc] = fmaf(xvt, wp[oc * 1152 + t], acc[oc]);
        }
    }
    int sp = (oh << 6) + ow;
#pragma unroll
    for (int oc = 0; oc < 27; ++oc)
        part[((((cg << 2) + n) * 27 + oc) << 12) + sp] = acc[oc];
}

// ---------------- K2: per-(tap,pos) meta ----------------
__global__ __launch_bounds__(256) void posprep(const float* __restrict__ part,
                                               const float* __restrict__ ob,
                                               float4* __restrict__ wq_t,
                                               ushort4* __restrict__ yx_t) {
    int gid = blockIdx.x * 256 + threadIdx.x;        // < 147456
    int k = gid >> 14, pos = gid & 16383;
    int n = pos >> 12, sp = pos & 4095;
    int oh = sp >> 6, ow = sp & 63;

    float oy = ob[2 * k], ox = ob[2 * k + 1], os = ob[18 + k];
#pragma unroll
    for (int cg = 0; cg < 16; ++cg) {
        const float* pb = part + ((((cg << 2) + n) * 27) << 12) + sp;
        oy += pb[(2 * k) << 12];
        ox += pb[(2 * k + 1) << 12];
        os += pb[(18 + k) << 12];
    }
    float m = 1.f / (1.f + expf(-os));
    float py = fminf(fmaxf((float)(oh + k / 3) + oy, 0.f), 65.f);
    float px = fminf(fmaxf((float)(ow + k % 3) + ox, 0.f), 65.f);
    float y1f = floorf(py), x1f = floorf(px);
    float lh = py - y1f, lw = px - x1f;
    float hh = 1.f - lh, hw = 1.f - lw;
    int y1 = (int)y1f, x1 = (int)x1f;
    int r1 = y1 - 1, r2 = y1, c1 = x1 - 1, c2 = x1;  // padded -> real coords
    bool vr1 = (unsigned)r1 < 64u, vr2 = (unsigned)r2 < 64u;
    bool vc1 = (unsigned)c1 < 64u, vc2 = (unsigned)c2 < 64u;
    float w1 = (vr1 && vc1) ? hh * hw * m : 0.f;
    float w2 = (vr1 && vc2) ? hh * lw * m : 0.f;
    float w3 = (vr2 && vc1) ? lh * hw * m : 0.f;
    float w4 = (vr2 && vc2) ? lh * lw * m : 0.f;
    int R1 = min(max(r1, 0), 63), R2 = min(max(r2, 0), 63);
    int C1 = min(max(c1, 0), 63), C2 = min(max(c2, 0), 63);
    wq_t[(k << 14) + pos] = make_float4(w1, w2, w3, w4);
    yx_t[(k << 14) + pos] = make_ushort4((unsigned short)R1, (unsigned short)R2,
                                         (unsigned short)C1, (unsigned short)C2);
}

// ---------------- K3: MFMA gather-GEMM ----------------
// grid 512 = 128 pos-tiles(128) x 4 kq. block 256 = 4 waves; wave = 64 pos x 64 out.
// kq = 9 ksteps of 32 k (each kstep within one tap). LDS dbuf A/B bf16 hi+lo, XOR-swizzled frags.
__global__ __launch_bounds__(256, 2) void dcn_main(const float* __restrict__ x,
                                                   const float4* __restrict__ wq_t,
                                                   const ushort4* __restrict__ yx_t,
                                                   const unsigned short* __restrict__ wbh,
                                                   const unsigned short* __restrict__ wbl,
                                                   float* __restrict__ pout) {
    __shared__ short Ah[2][4096], Al[2][4096];       // [pos 128][k 32] bf16, swizzled 16B groups
    __shared__ short Bh[2][4096], Bl[2][4096];       // [o 128][k 32] bf16, pre-swizzled source

    int b0 = blockIdx.x;
    int bid = ((b0 & 7) << 6) | (b0 >> 3);           // XCD swizzle (512 = 8*64)
    int tile = bid >> 2, q = bid & 3;
    int p0 = tile << 7;
    int tid = threadIdx.x;
    int lane = tid & 63, wave = tid >> 6;
    int ph = wave >> 1, ohf = wave & 1;              // pos-half, o-half
    int fr = lane & 15, fg = lane >> 4;              // frag row/col, k-group

    int gp = tid & 127, gc = tid >> 7;               // gather: pos_local, ch-group-of-16
    int pos = p0 + gp;
    int n = pos >> 12;                               // block-uniform (128 | 4096)
    const float* xn = x + ((long)n << 19);

    int S0 = q * 9;

    f32x4 acc[4][4];
#pragma unroll
    for (int i = 0; i < 4; ++i)
#pragma unroll
        for (int j = 0; j < 4; ++j) acc[i][j] = (f32x4)0.f;

    float gv[16][4];
    float4 wv;
    bf16x8 bsh0, bsh1, bsl0, bsl1;

#define ISSUE_GATHER(S_) do {                                                      \
    int t_ = (S_) >> 2;                                                            \
    wv = wq_t[(t_ << 14) + pos];                                                   \
    ushort4 yx_ = yx_t[(t_ << 14) + pos];                                          \
    int o1_ = ((int)yx_.x << 6) + yx_.z, o2_ = ((int)yx_.x << 6) + yx_.w;          \
    int o3_ = ((int)yx_.y << 6) + yx_.z, o4_ = ((int)yx_.y << 6) + yx_.w;          \
    const float* xb_ = xn + ((long)((((S_) & 3) << 5) + (gc << 4)) << 12);         \
    _Pragma("unroll")                                                              \
    for (int c_ = 0; c_ < 16; ++c_) {                                              \
        const float* xc_ = xb_ + (c_ << 12);                                       \
        gv[c_][0] = xc_[o1_]; gv[c_][1] = xc_[o2_];                                \
        gv[c_][2] = xc_[o3_]; gv[c_][3] = xc_[o4_];                                \
    }                                                                              \
} while (0)

#define STAGE_B_LOAD(S_) do {                                                      \
    const bf16x8* sh_ = (const bf16x8*)(wbh + ((long)(S_) << 12));                 \
    const bf16x8* sl_ = (const bf16x8*)(wbl + ((long)(S_) << 12));                 \
    bsh0 = sh_[tid]; bsh1 = sh_[tid + 256];                                        \
    bsl0 = sl_[tid]; bsl1 = sl_[tid + 256];                                        \
} while (0)

#define STAGE_B_WRITE(bufi) do {                                                   \
    *(bf16x8*)&Bh[bufi][tid << 3] = bsh0;                                          \
    *(bf16x8*)&Bh[bufi][(tid << 3) + 2048] = bsh1;                                 \
    *(bf16x8*)&Bl[bufi][tid << 3] = bsl0;                                          \
    *(bf16x8*)&Bl[bufi][(tid << 3) + 2048] = bsl1;                                 \
} while (0)

#define PACK_WRITE_A(bufi) do {                                                    \
    _Pragma("unroll")                                                              \
    for (int h_ = 0; h_ < 2; ++h_) {                                               \
        bf16x8 vh_, vl_;                                                           \
        _Pragma("unroll")                                                          \
        for (int e_ = 0; e_ < 8; ++e_) {                                           \
            int c_ = h_ * 8 + e_;                                                  \
            float v_ = wv.x * gv[c_][0] + wv.y * gv[c_][1]                         \
                     + wv.z * gv[c_][2] + wv.w * gv[c_][3];                        \
            unsigned short hh_ = f2bf(v_);                                         \
            vh_[e_] = (short)hh_;                                                  \
            vl_[e_] = (short)f2bf(v_ - bf2f(hh_));                                 \
        }                                                                          \
        int G_ = (gc << 1) + h_;                                                   \
        int sl_ = (G_ ^ (gp & 3)) << 3;                                            \
        *(bf16x8*)&Ah[bufi][(gp << 5) + sl_] = vh_;                                \
        *(bf16x8*)&Al[bufi][(gp << 5) + sl_] = vl_;                                \
    }                                                                              \
} while (0)

    // prologue: kstep S0
    STAGE_B_LOAD(S0);
    ISSUE_GATHER(S0);
    PACK_WRITE_A(0);
    STAGE_B_WRITE(0);
    __syncthreads();

#pragma unroll 1
    for (int s = 0; s < 9; ++s) {
        int buf = s & 1, nxt = buf ^ 1;
        if (s < 8) {
            STAGE_B_LOAD(S0 + s + 1);                // issue early (T14)
            ISSUE_GATHER(S0 + s + 1);
        }
        bf16x8 ah[4], al[4];
#pragma unroll
        for (int i = 0; i < 4; ++i) {
            int pl = (ph << 6) + (i << 4) + fr;
            int sl = (fg ^ (pl & 3)) << 3;
            ah[i] = *(const bf16x8*)&Ah[buf][(pl << 5) + sl];
            al[i] = *(const bf16x8*)&Al[buf][(pl << 5) + sl];
        }
#pragma unroll
        for (int j = 0; j < 4; ++j) {
            int ob = (ohf << 6) + (j << 4) + fr;
            int sl = (fg ^ (ob & 3)) << 3;
            bf16x8 bh = *(const bf16x8*)&Bh[buf][(ob << 5) + sl];
            bf16x8 bl = *(const bf16x8*)&Bl[buf][(ob << 5) + sl];
#pragma unroll
            for (int i = 0; i < 4; ++i) {
                acc[i][j] = __builtin_amdgcn_mfma_f32_16x16x32_bf16(ah[i], bh, acc[i][j], 0, 0, 0);
                acc[i][j] = __builtin_amdgcn_mfma_f32_16x16x32_bf16(al[i], bh, acc[i][j], 0, 0, 0);
                acc[i][j] = __builtin_amdgcn_mfma_f32_16x16x32_bf16(ah[i], bl, acc[i][j], 0, 0, 0);
            }
        }
        if (s < 8) {
            PACK_WRITE_A(nxt);                       // write late (after MFMA)
            STAGE_B_WRITE(nxt);
        }
        __syncthreads();
    }

    // epilogue: pout[q][o][pos] (o-major) — each lane stores contiguous float4 (4 consecutive pos)
    float* op = pout + ((long)q << 21);
#pragma unroll
    for (int i = 0; i < 4; ++i) {
        int pp = p0 + (ph << 6) + (i << 4) + (fg << 2);
#pragma unroll
        for (int j = 0; j < 4; ++j) {
            int o = (ohf << 6) + (j << 4) + fr;
            float4 st = make_float4(acc[i][j][0], acc[i][j][1], acc[i][j][2], acc[i][j][3]);
            *(float4*)(op + ((long)o << 14) + pp) = st;
        }
    }
#undef ISSUE_GATHER
#undef STAGE_B_LOAD
#undef STAGE_B_WRITE
#undef PACK_WRITE_A
}

// ---------------- K4: sum 4 K-partials, fully coalesced ----------------
// pout[q][o][pos], pos = n*4096+hw ; out[n][o][hw]. grid 2048 x 256 over float4s.
__global__ __launch_bounds__(256) void combine(const float4* __restrict__ pout4,
                                               float4* __restrict__ out4) {
    int i = blockIdx.x * 256 + threadIdx.x;          // < 524288
    int o = i >> 12, rem = i & 4095;
    int n = rem >> 10, hw4 = rem & 1023;
    float4 a = pout4[i];
    float4 b = pout4[i + (1 << 19)];
    float4 c = pout4[i + (2 << 19)];
    float4 d = pout4[i + (3 << 19)];
    float4 r = make_float4(a.x + b.x + c.x + d.x, a.y + b.y + c.y + d.y,
                           a.z + b.z + c.z + d.z, a.w + b.w + c.w + d.w);
    out4[(n << 17) + (o << 10) + hw4] = r;
}

extern "C" void kernel_launch(void* const* d_in, const int* in_sizes, int n_in,
                              void* d_out, int out_size, void* d_ws, size_t ws_size,
                              hipStream_t stream) {
    const float* x     = (const float*)d_in[0];      // [4,128,64,64]
    const float* ofw   = (const float*)d_in[1];      // [27,128,3,3]
    const float* ob    = (const float*)d_in[2];      // [27]
    const float* dcn_w = (const float*)d_in[3];      // [128,128,3,3]
    float* out = (float*)d_out;                      // [4,128,64,64]

    char* ws = (char*)d_ws;
    // pout (K3/K4) overlaps part (K1/K2) — disjoint lifetimes
    float*          pout = (float*)ws;               // 4*2^21*4    = 33,554,432 B
    float*          part = (float*)ws;               // 16*4*27*4096*4 = 28,311,552 B (overlap)
    float4*         wq_t = (float4*)(ws + 33554432); // 2,359,296 B
    ushort4*        yx_t = (ushort4*)(ws + 35913728);// 1,179,648 B
    unsigned short* wbh  = (unsigned short*)(ws + 37093376); // 294,912 B
    unsigned short* wbl  = (unsigned short*)(ws + 37388288); // 294,912 B
    // total 37,683,200 B

    offconv_prep<<<dim3(1600), dim3(256), 0, stream>>>(x, ofw, dcn_w, part, wbh, wbl);
    posprep<<<dim3(576), dim3(256), 0, stream>>>(part, ob, wq_t, yx_t);
    dcn_main<<<dim3(512), dim3(256), 0, stream>>>(x, wq_t, yx_t, wbh, wbl, pout);
    combine<<<dim3(2048), dim3(256), 0, stream>>>((const float4*)pout, (float4*)out);
}